// Round 1
// baseline (2102.356 us; speedup 1.0000x reference)
//
#include <hip/hip_runtime.h>

#define D 512
#define HEADS 8
#define DK 64
#define BATCH 2
#define SEQ 4096
#define M_TOT (BATCH * SEQ)   // 8192

// ---------------------------------------------------------------------------
// QKV projection: Out = x @ W^T, written head-major [B*H, T, DK].
// Tile 64x64, K-step 16, 256 threads, each thread 4x4 micro-tile.
// ---------------------------------------------------------------------------
__global__ __launch_bounds__(256) void qkv_gemm(
    const float* __restrict__ x,
    const float* __restrict__ Wq, const float* __restrict__ Wk,
    const float* __restrict__ Wv,
    float* __restrict__ Qh, float* __restrict__ Kh, float* __restrict__ Vh)
{
    const int which = blockIdx.z;
    const float* W = (which == 0) ? Wq : ((which == 1) ? Wk : Wv);
    float* Out = (which == 0) ? Qh : ((which == 1) ? Kh : Vh);

    const int m0 = blockIdx.x * 64;
    const int n0 = blockIdx.y * 64;
    const int tid = threadIdx.x;
    const int ty = tid >> 4;        // 0..15
    const int tx = tid & 15;        // 0..15
    const int lr = tid >> 2;        // 0..63 load row
    const int lk = (tid & 3) << 2;  // 0,4,8,12 load col

    __shared__ float As[16][64];    // As[k][m]
    __shared__ float Bs[16][64];    // Bs[k][n]

    float acc[4][4] = {};

    for (int k0 = 0; k0 < D; k0 += 16) {
        float4 av = *(const float4*)(x + (size_t)(m0 + lr) * D + k0 + lk);
        float4 bv = *(const float4*)(W + (size_t)(n0 + lr) * D + k0 + lk);
        __syncthreads();
        As[lk + 0][lr] = av.x; As[lk + 1][lr] = av.y;
        As[lk + 2][lr] = av.z; As[lk + 3][lr] = av.w;
        Bs[lk + 0][lr] = bv.x; Bs[lk + 1][lr] = bv.y;
        Bs[lk + 2][lr] = bv.z; Bs[lk + 3][lr] = bv.w;
        __syncthreads();
        #pragma unroll
        for (int kk = 0; kk < 16; ++kk) {
            float4 a = *(const float4*)&As[kk][ty * 4];
            float4 b = *(const float4*)&Bs[kk][tx * 4];
            float ar[4] = {a.x, a.y, a.z, a.w};
            float br[4] = {b.x, b.y, b.z, b.w};
            #pragma unroll
            for (int i = 0; i < 4; ++i)
                #pragma unroll
                for (int j = 0; j < 4; ++j)
                    acc[i][j] = fmaf(ar[i], br[j], acc[i][j]);
        }
    }

    #pragma unroll
    for (int i = 0; i < 4; ++i) {
        const int m = m0 + ty * 4 + i;
        const int b = m >> 12;          // /4096
        const int t = m & 4095;
        #pragma unroll
        for (int j = 0; j < 4; ++j) {
            const int n = n0 + tx * 4 + j;
            const int h = n >> 6;
            const int d = n & 63;
            Out[(((size_t)(b * HEADS + h) * SEQ) + t) * DK + d] = acc[i][j];
        }
    }
}

// ---------------------------------------------------------------------------
// Flash attention (fp32): one block = one (bh, 64-row Q tile).
// 256 threads: thread (r = tid/4, g = tid%4) owns score cols c = g + 4*c1
// and output cols d = g*16 .. g*16+15 of row r. Online softmax; P is
// intra-wave (row group = 4 consecutive lanes) so no barrier for P.
// Output written directly in [B, T, D] layout.
// ---------------------------------------------------------------------------
__global__ __launch_bounds__(256) void flash_fwd(
    const float* __restrict__ Qh, const float* __restrict__ Kh,
    const float* __restrict__ Vh, float* __restrict__ Ow)
{
    const int bh = blockIdx.y;       // 0..15
    const int q0 = blockIdx.x * 64;
    const int tid = threadIdx.x;
    const int r = tid >> 2;          // 0..63
    const int g = tid & 3;           // 0..3

    __shared__ float Qs[64][68];
    __shared__ float Ks[64][68];
    __shared__ float Vs[64][68];
    __shared__ float Ps[64][68];

    const float* Qp = Qh + ((size_t)bh * SEQ + q0) * DK;
    const float* Kbase = Kh + (size_t)bh * SEQ * DK;
    const float* Vbase = Vh + (size_t)bh * SEQ * DK;

    // Load Q tile (coalesced: 16 lanes cover one 256B row)
    {
        const int f = tid & 15;
        const int r0 = tid >> 4;
        #pragma unroll
        for (int rr = 0; rr < 4; ++rr) {
            const int row = r0 + rr * 16;
            float4 v = *(const float4*)(Qp + row * DK + f * 4);
            *(float4*)&Qs[row][f * 4] = v;
        }
    }

    float m_run = -1e30f, l_run = 0.f;
    float o[16];
    #pragma unroll
    for (int i = 0; i < 16; ++i) o[i] = 0.f;

    for (int k0 = 0; k0 < SEQ; k0 += 64) {
        __syncthreads();   // previous tile's PV reads done before overwrite
        {
            const int f = tid & 15;
            const int r0 = tid >> 4;
            #pragma unroll
            for (int rr = 0; rr < 4; ++rr) {
                const int row = r0 + rr * 16;
                float4 kv = *(const float4*)(Kbase + (size_t)(k0 + row) * DK + f * 4);
                float4 vv = *(const float4*)(Vbase + (size_t)(k0 + row) * DK + f * 4);
                *(float4*)&Ks[row][f * 4] = kv;
                *(float4*)&Vs[row][f * 4] = vv;
            }
        }
        __syncthreads();

        // Scores s[c1] for c = g + 4*c1  (lane-g row interleave: conflict-free)
        float s[16];
        #pragma unroll
        for (int i = 0; i < 16; ++i) s[i] = 0.f;
        #pragma unroll
        for (int k4 = 0; k4 < 16; ++k4) {
            float4 qv = *(const float4*)&Qs[r][k4 * 4];
            #pragma unroll
            for (int c1 = 0; c1 < 16; ++c1) {
                float4 kv = *(const float4*)&Ks[g + 4 * c1][k4 * 4];
                s[c1] += qv.x * kv.x + qv.y * kv.y + qv.z * kv.z + qv.w * kv.w;
            }
        }

        // Online softmax (scale 1/sqrt(64) = 0.125)
        float tmax = -1e30f;
        #pragma unroll
        for (int i = 0; i < 16; ++i) { s[i] *= 0.125f; tmax = fmaxf(tmax, s[i]); }
        tmax = fmaxf(tmax, __shfl_xor(tmax, 1));
        tmax = fmaxf(tmax, __shfl_xor(tmax, 2));
        const float m_new = fmaxf(m_run, tmax);
        const float corr = __expf(m_run - m_new);
        float psum = 0.f;
        #pragma unroll
        for (int c1 = 0; c1 < 16; ++c1) {
            const float p = __expf(s[c1] - m_new);
            Ps[r][g + 4 * c1] = p;
            psum += p;
        }
        psum += __shfl_xor(psum, 1);
        psum += __shfl_xor(psum, 2);
        l_run = l_run * corr + psum;
        m_run = m_new;
        #pragma unroll
        for (int i = 0; i < 16; ++i) o[i] *= corr;

        // PV: o[d'] += sum_c P[r][c] * V[c][g*16+d']   (P intra-wave)
        #pragma unroll 16
        for (int c = 0; c < 64; ++c) {
            const float pv = Ps[r][c];
            #pragma unroll
            for (int dd = 0; dd < 4; ++dd) {
                float4 vv = *(const float4*)&Vs[c][g * 16 + dd * 4];
                o[dd * 4 + 0] = fmaf(pv, vv.x, o[dd * 4 + 0]);
                o[dd * 4 + 1] = fmaf(pv, vv.y, o[dd * 4 + 1]);
                o[dd * 4 + 2] = fmaf(pv, vv.z, o[dd * 4 + 2]);
                o[dd * 4 + 3] = fmaf(pv, vv.w, o[dd * 4 + 3]);
            }
        }
    }

    // Epilogue: write [B, T, D] layout
    const int b = bh >> 3, h = bh & 7;
    const float inv_l = 1.f / l_run;
    float* dst = Ow + ((size_t)(b * SEQ) + q0 + r) * D + h * DK + g * 16;
    #pragma unroll
    for (int dd = 0; dd < 4; ++dd) {
        float4 v = make_float4(o[dd * 4 + 0] * inv_l, o[dd * 4 + 1] * inv_l,
                               o[dd * 4 + 2] * inv_l, o[dd * 4 + 3] * inv_l);
        *(float4*)(dst + dd * 4) = v;
    }
}

// ---------------------------------------------------------------------------
// Output projection: C = A[8192,512] @ Wo[512,512]^T (standard layout)
// ---------------------------------------------------------------------------
__global__ __launch_bounds__(256) void out_gemm(
    const float* __restrict__ A, const float* __restrict__ Wo,
    float* __restrict__ C)
{
    const int m0 = blockIdx.x * 64;
    const int n0 = blockIdx.y * 64;
    const int tid = threadIdx.x;
    const int ty = tid >> 4;
    const int tx = tid & 15;
    const int lr = tid >> 2;
    const int lk = (tid & 3) << 2;

    __shared__ float As[16][64];
    __shared__ float Bs[16][64];

    float acc[4][4] = {};

    for (int k0 = 0; k0 < D; k0 += 16) {
        float4 av = *(const float4*)(A + (size_t)(m0 + lr) * D + k0 + lk);
        float4 bv = *(const float4*)(Wo + (size_t)(n0 + lr) * D + k0 + lk);
        __syncthreads();
        As[lk + 0][lr] = av.x; As[lk + 1][lr] = av.y;
        As[lk + 2][lr] = av.z; As[lk + 3][lr] = av.w;
        Bs[lk + 0][lr] = bv.x; Bs[lk + 1][lr] = bv.y;
        Bs[lk + 2][lr] = bv.z; Bs[lk + 3][lr] = bv.w;
        __syncthreads();
        #pragma unroll
        for (int kk = 0; kk < 16; ++kk) {
            float4 a = *(const float4*)&As[kk][ty * 4];
            float4 b = *(const float4*)&Bs[kk][tx * 4];
            float ar[4] = {a.x, a.y, a.z, a.w};
            float br[4] = {b.x, b.y, b.z, b.w};
            #pragma unroll
            for (int i = 0; i < 4; ++i)
                #pragma unroll
                for (int j = 0; j < 4; ++j)
                    acc[i][j] = fmaf(ar[i], br[j], acc[i][j]);
        }
    }

    #pragma unroll
    for (int i = 0; i < 4; ++i) {
        const int m = m0 + ty * 4 + i;
        #pragma unroll
        for (int j = 0; j < 4; ++j) {
            const int n = n0 + tx * 4 + j;
            C[(size_t)m * D + n] = acc[i][j];
        }
    }
}

extern "C" void kernel_launch(void* const* d_in, const int* in_sizes, int n_in,
                              void* d_out, int out_size, void* d_ws, size_t ws_size,
                              hipStream_t stream)
{
    const float* x  = (const float*)d_in[0];
    const float* Wq = (const float*)d_in[1];
    const float* Wk = (const float*)d_in[2];
    const float* Wv = (const float*)d_in[3];
    const float* Wo = (const float*)d_in[4];
    float* out = (float*)d_out;

    const size_t per = (size_t)BATCH * HEADS * SEQ * DK;  // 4,194,304 floats
    float* Qh = (float*)d_ws;
    float* Kh = Qh + per;
    float* Vh = Kh + per;
    float* Ow = Vh + per;   // attention output in [B, T, D] layout

    qkv_gemm<<<dim3(M_TOT / 64, D / 64, 3), 256, 0, stream>>>(x, Wq, Wk, Wv, Qh, Kh, Vh);
    flash_fwd<<<dim3(SEQ / 64, BATCH * HEADS), 256, 0, stream>>>(Qh, Kh, Vh, Ow);
    out_gemm<<<dim3(M_TOT / 64, D / 64), 256, 0, stream>>>(Ow, Wo, out);
}

// Round 2
// 271.463 us; speedup vs baseline: 7.7446x; 7.7446x over previous
//
#include <hip/hip_runtime.h>
#include <hip/hip_bf16.h>

#define SEQ 4096
#define DMODEL 512
#define HEADS 8
#define DK 64
#define BATCH 2
#define MTOT (BATCH * SEQ)     // 8192
#define NBH (BATCH * HEADS)    // 16

typedef __attribute__((ext_vector_type(8))) short bh8;   // 8 bf16 in 4 VGPRs
typedef __attribute__((ext_vector_type(4))) float f4;

#define MFMA(a, b, c) __builtin_amdgcn_mfma_f32_16x16x32_bf16(a, b, c, 0, 0, 0)
#define GLL16(g, l) __builtin_amdgcn_global_load_lds( \
    (const __attribute__((address_space(1))) void*)(g), \
    (__attribute__((address_space(3))) void*)(l), 16, 0, 0)

__device__ __forceinline__ unsigned short f2b(float f) {
    union { float f; unsigned u; } v; v.f = f;
    unsigned r = v.u + 0x7fff + ((v.u >> 16) & 1);   // RNE, inputs are finite
    return (unsigned short)(r >> 16);
}

// ---------------------------------------------------------------------------
// fp32 -> bf16 conversion of x and the 4 weight matrices into one ws region.
// dst layout: [x(4194304) | wq(262144) | wk | wv | wo]
// ---------------------------------------------------------------------------
__global__ __launch_bounds__(256) void convert_k(
    const float* __restrict__ x, const float* __restrict__ wq,
    const float* __restrict__ wk, const float* __restrict__ wv,
    const float* __restrict__ wo, unsigned short* __restrict__ dst)
{
    const size_t i = ((size_t)blockIdx.x * 256 + threadIdx.x) * 4;
    const float* s; size_t o;
    if (i < 4194304u)                 { s = x;  o = i; }
    else if (i < 4194304u + 262144u)  { s = wq; o = i - 4194304u; }
    else if (i < 4194304u + 524288u)  { s = wk; o = i - (4194304u + 262144u); }
    else if (i < 4194304u + 786432u)  { s = wv; o = i - (4194304u + 524288u); }
    else                              { s = wo; o = i - (4194304u + 786432u); }
    float4 v = *(const float4*)(s + o);
    ushort4 u; u.x = f2b(v.x); u.y = f2b(v.y); u.z = f2b(v.z); u.w = f2b(v.w);
    *(ushort4*)(dst + i) = u;
}

// ---------------------------------------------------------------------------
// C = A[8192,512] @ B[512,512]^T via 16x16x32 bf16 MFMA. 128x128 tile, BK=32,
// 4 waves (2x2 of 64x64). global_load_lds(16B) staging with pre-swizzled
// global source; LDS rows 64B = 4 slots, slot ^= (row>>1)&3.
// Epilogue: head-major bf16 [z][b*8+h][t][d], Q pre-scaled by 0.125.
// ---------------------------------------------------------------------------
__global__ __launch_bounds__(256) void qkv_gemm_mfma(
    const unsigned short* __restrict__ xb,   // [8192][512]
    const unsigned short* __restrict__ Wb,   // [3+][512][512] q,k,v
    unsigned short* __restrict__ QKV)        // [3][NBH][SEQ][DK]
{
    const int z = blockIdx.z;
    const unsigned short* A = xb;
    const unsigned short* B = Wb + (size_t)z * (DMODEL * DMODEL);
    const int m0 = blockIdx.x * 128, n0 = blockIdx.y * 128;
    const int tid = threadIdx.x, w = tid >> 6, l = tid & 63;
    const int wr = w >> 1, wc = w & 1;

    __shared__ __align__(16) unsigned short As[128 * 32];
    __shared__ __align__(16) unsigned short Bs[128 * 32];

    f4 acc[4][4] = {};
    const int lrow = l >> 2, lslot = l & 3;

    for (int k0 = 0; k0 < DMODEL; k0 += 32) {
        __syncthreads();
        #pragma unroll
        for (int j = 0; j < 2; ++j) {
            const int row = w * 32 + j * 16 + lrow;
            const int sw = lslot ^ ((row >> 1) & 3);
            GLL16(A + (size_t)(m0 + row) * DMODEL + k0 + sw * 8,
                  (char*)As + (w * 32 + j * 16) * 64);
            GLL16(B + (size_t)(n0 + row) * DMODEL + k0 + sw * 8,
                  (char*)Bs + (w * 32 + j * 16) * 64);
        }
        __syncthreads();
        bh8 af[4], bg[4];
        #pragma unroll
        for (int mi = 0; mi < 4; ++mi) {
            const int r = wr * 64 + mi * 16 + (l & 15);
            af[mi] = *(const bh8*)((const char*)As + r * 64 +
                                   (((l >> 4) * 16) ^ (((r >> 1) & 3) << 4)));
        }
        #pragma unroll
        for (int ni = 0; ni < 4; ++ni) {
            const int r = wc * 64 + ni * 16 + (l & 15);
            bg[ni] = *(const bh8*)((const char*)Bs + r * 64 +
                                   (((l >> 4) * 16) ^ (((r >> 1) & 3) << 4)));
        }
        #pragma unroll
        for (int mi = 0; mi < 4; ++mi)
            #pragma unroll
            for (int ni = 0; ni < 4; ++ni)
                acc[mi][ni] = MFMA(af[mi], bg[ni], acc[mi][ni]);
    }

    unsigned short* Out = QKV + (size_t)z * ((size_t)NBH * SEQ * DK);
    const float sc = (z == 0) ? 0.125f : 1.0f;   // fold 1/sqrt(dk) into Q (exact)
    #pragma unroll
    for (int mi = 0; mi < 4; ++mi) {
        #pragma unroll
        for (int rg = 0; rg < 4; ++rg) {
            const int m = m0 + wr * 64 + mi * 16 + (l >> 4) * 4 + rg;
            const int b = m >> 12, t = m & (SEQ - 1);
            #pragma unroll
            for (int ni = 0; ni < 4; ++ni) {
                const int n = n0 + wc * 64 + ni * 16 + (l & 15);
                const int h = n >> 6, d = n & 63;
                Out[(((size_t)(b * HEADS + h)) * SEQ + t) * DK + d] =
                    f2b(acc[mi][ni][rg] * sc);
            }
        }
    }
}

// ---------------------------------------------------------------------------
// V [bh][t][d] -> Vt [bh][d][t], 64x64 LDS tiles, coalesced both sides.
// ---------------------------------------------------------------------------
__global__ __launch_bounds__(256) void vtrans(
    const unsigned short* __restrict__ Vh, unsigned short* __restrict__ Vt)
{
    const int bh = blockIdx.y, t0 = blockIdx.x * 64;
    __shared__ unsigned short L[64][72];
    const unsigned short* src = Vh + ((size_t)bh * SEQ + t0) * DK;
    const int r = threadIdx.x >> 3, c8 = (threadIdx.x & 7) * 8;
    #pragma unroll
    for (int it = 0; it < 2; ++it) {
        const int row = r + it * 32;
        ushort4 a = *(const ushort4*)(src + (size_t)row * DK + c8);
        ushort4 b = *(const ushort4*)(src + (size_t)row * DK + c8 + 4);
        L[row][c8 + 0] = a.x; L[row][c8 + 1] = a.y; L[row][c8 + 2] = a.z; L[row][c8 + 3] = a.w;
        L[row][c8 + 4] = b.x; L[row][c8 + 5] = b.y; L[row][c8 + 6] = b.z; L[row][c8 + 7] = b.w;
    }
    __syncthreads();
    unsigned short* dst = Vt + (size_t)bh * DK * SEQ + t0;
    #pragma unroll
    for (int it = 0; it < 2; ++it) {
        const int d = r + it * 32;
        ushort4 a, b;
        a.x = L[c8 + 0][d]; a.y = L[c8 + 1][d]; a.z = L[c8 + 2][d]; a.w = L[c8 + 3][d];
        b.x = L[c8 + 4][d]; b.y = L[c8 + 5][d]; b.z = L[c8 + 6][d]; b.w = L[c8 + 7][d];
        *(ushort4*)(dst + (size_t)d * SEQ + c8) = a;
        *(ushort4*)(dst + (size_t)d * SEQ + c8 + 4) = b;
    }
}

// ---------------------------------------------------------------------------
// Flash attention, bf16 MFMA. Block = (bh, 128 q-rows); 4 waves x 32 rows.
// Q frags hoisted to registers; K/V tiles (64x64) staged via swizzled
// global_load_lds; online softmax (4x shfl_xor over 16-lane group); P via
// XOR-swizzled LDS (same-wave only). LDS rows 128B = 8 slots, slot ^= row&7.
// ---------------------------------------------------------------------------
__global__ __launch_bounds__(256) void flash_mfma(
    const unsigned short* __restrict__ Qh,   // [NBH][SEQ][DK], pre-scaled
    const unsigned short* __restrict__ Kh,   // [NBH][SEQ][DK]
    const unsigned short* __restrict__ Vtp,  // [NBH][DK][SEQ]
    unsigned short* __restrict__ Ow)         // [MTOT][DMODEL]
{
    const int bh = blockIdx.y, q0 = blockIdx.x * 128;
    const int tid = threadIdx.x, w = tid >> 6, l = tid & 63;
    __shared__ __align__(16) unsigned short Ks[64 * 64];   // [kv][dk] swz
    __shared__ __align__(16) unsigned short Vs[64 * 64];   // [d][kv] swz
    __shared__ __align__(16) unsigned short Ps[128 * 64];  // [q][kv] swz
    const unsigned short* Qb = Qh + (size_t)bh * SEQ * DK;
    const unsigned short* Kb = Kh + (size_t)bh * SEQ * DK;
    const unsigned short* Vb = Vtp + (size_t)bh * DK * SEQ;

    bh8 qf[2][2];
    #pragma unroll
    for (int mi = 0; mi < 2; ++mi)
        #pragma unroll
        for (int kc = 0; kc < 2; ++kc) {
            const int q = q0 + w * 32 + mi * 16 + (l & 15);
            qf[mi][kc] = *(const bh8*)(Qb + (size_t)q * DK + kc * 32 + (l >> 4) * 8);
        }

    f4 o[2][4] = {};
    float m_run[2][4], l_run[2][4];
    #pragma unroll
    for (int mi = 0; mi < 2; ++mi)
        #pragma unroll
        for (int rg = 0; rg < 4; ++rg) { m_run[mi][rg] = -3.0e38f; l_run[mi][rg] = 0.f; }

    const int srow = l >> 3, sslot = l & 7;

    for (int kv0 = 0; kv0 < SEQ; kv0 += 64) {
        __syncthreads();
        #pragma unroll
        for (int j = 0; j < 2; ++j) {
            const int row = w * 16 + j * 8 + srow;
            const int sw = sslot ^ (row & 7);
            GLL16(Kb + (size_t)(kv0 + row) * DK + sw * 8,
                  (char*)Ks + (w * 16 + j * 8) * 128);
            GLL16(Vb + (size_t)row * SEQ + kv0 + sw * 8,
                  (char*)Vs + (w * 16 + j * 8) * 128);
        }
        __syncthreads();

        // S = Q K^T  (scale already folded into Q)
        f4 sacc[2][4] = {};
        #pragma unroll
        for (int kc = 0; kc < 2; ++kc)
            #pragma unroll
            for (int cb = 0; cb < 4; ++cb) {
                const int kvr = cb * 16 + (l & 15);
                bh8 kf = *(const bh8*)((const char*)Ks + kvr * 128 +
                         ((kc * 64 + (l >> 4) * 16) ^ ((kvr & 7) << 4)));
                #pragma unroll
                for (int mi = 0; mi < 2; ++mi)
                    sacc[mi][cb] = MFMA(qf[mi][kc], kf, sacc[mi][cb]);
            }

        // online softmax; rows of a 16-block live in 16-lane groups
        #pragma unroll
        for (int mi = 0; mi < 2; ++mi) {
            float corr[4];
            #pragma unroll
            for (int rg = 0; rg < 4; ++rg) {
                float s0 = sacc[mi][0][rg], s1 = sacc[mi][1][rg];
                float s2 = sacc[mi][2][rg], s3 = sacc[mi][3][rg];
                float mx = fmaxf(fmaxf(s0, s1), fmaxf(s2, s3));
                mx = fmaxf(mx, __shfl_xor(mx, 1));
                mx = fmaxf(mx, __shfl_xor(mx, 2));
                mx = fmaxf(mx, __shfl_xor(mx, 4));
                mx = fmaxf(mx, __shfl_xor(mx, 8));
                const float mnew = fmaxf(m_run[mi][rg], mx);
                const float c = __expf(m_run[mi][rg] - mnew);
                m_run[mi][rg] = mnew;
                const float p0 = __expf(s0 - mnew), p1 = __expf(s1 - mnew);
                const float p2 = __expf(s2 - mnew), p3 = __expf(s3 - mnew);
                float ps = p0 + p1 + p2 + p3;
                ps += __shfl_xor(ps, 1); ps += __shfl_xor(ps, 2);
                ps += __shfl_xor(ps, 4); ps += __shfl_xor(ps, 8);
                l_run[mi][rg] = l_run[mi][rg] * c + ps;
                corr[rg] = c;
                const int q = w * 32 + mi * 16 + (l >> 4) * 4 + rg;
                char* pb = (char*)Ps + q * 128;
                const int sx = (q & 7) << 4;
                *(unsigned short*)(pb + ((((l & 15)     ) * 2) ^ sx)) = f2b(p0);
                *(unsigned short*)(pb + ((((l & 15) + 16) * 2) ^ sx)) = f2b(p1);
                *(unsigned short*)(pb + ((((l & 15) + 32) * 2) ^ sx)) = f2b(p2);
                *(unsigned short*)(pb + ((((l & 15) + 48) * 2) ^ sx)) = f2b(p3);
            }
            #pragma unroll
            for (int db = 0; db < 4; ++db)
                #pragma unroll
                for (int rg = 0; rg < 4; ++rg)
                    o[mi][db][rg] *= corr[rg];
        }

        // O += P V   (P frags from swizzled LDS, same wave -> no barrier)
        bh8 pf[2][2];
        #pragma unroll
        for (int mi = 0; mi < 2; ++mi)
            #pragma unroll
            for (int kc = 0; kc < 2; ++kc) {
                const int q = w * 32 + mi * 16 + (l & 15);
                pf[mi][kc] = *(const bh8*)((const char*)Ps + q * 128 +
                             ((kc * 64 + (l >> 4) * 16) ^ ((q & 7) << 4)));
            }
        #pragma unroll
        for (int kc = 0; kc < 2; ++kc)
            #pragma unroll
            for (int db = 0; db < 4; ++db) {
                const int d = db * 16 + (l & 15);
                bh8 vf = *(const bh8*)((const char*)Vs + d * 128 +
                         ((kc * 64 + (l >> 4) * 16) ^ ((d & 7) << 4)));
                #pragma unroll
                for (int mi = 0; mi < 2; ++mi)
                    o[mi][db] = MFMA(pf[mi][kc], vf, o[mi][db]);
            }
    }

    const int b = bh >> 3, h = bh & 7;
    #pragma unroll
    for (int mi = 0; mi < 2; ++mi) {
        #pragma unroll
        for (int rg = 0; rg < 4; ++rg) {
            const float inv = 1.0f / l_run[mi][rg];
            const int t = q0 + w * 32 + mi * 16 + (l >> 4) * 4 + rg;
            unsigned short* dst = Ow + ((size_t)b * SEQ + t) * DMODEL + h * DK;
            #pragma unroll
            for (int db = 0; db < 4; ++db)
                dst[db * 16 + (l & 15)] = f2b(o[mi][db][rg] * inv);
        }
    }
}

// ---------------------------------------------------------------------------
// out = Ow[8192,512](bf16) @ Wo[512,512]^T(bf16) -> fp32. Same GEMM structure.
// ---------------------------------------------------------------------------
__global__ __launch_bounds__(256) void out_gemm_mfma(
    const unsigned short* __restrict__ Ob,
    const unsigned short* __restrict__ Wob,
    float* __restrict__ out)
{
    const int m0 = blockIdx.x * 128, n0 = blockIdx.y * 128;
    const int tid = threadIdx.x, w = tid >> 6, l = tid & 63;
    const int wr = w >> 1, wc = w & 1;

    __shared__ __align__(16) unsigned short As[128 * 32];
    __shared__ __align__(16) unsigned short Bs[128 * 32];

    f4 acc[4][4] = {};
    const int lrow = l >> 2, lslot = l & 3;

    for (int k0 = 0; k0 < DMODEL; k0 += 32) {
        __syncthreads();
        #pragma unroll
        for (int j = 0; j < 2; ++j) {
            const int row = w * 32 + j * 16 + lrow;
            const int sw = lslot ^ ((row >> 1) & 3);
            GLL16(Ob + (size_t)(m0 + row) * DMODEL + k0 + sw * 8,
                  (char*)As + (w * 32 + j * 16) * 64);
            GLL16(Wob + (size_t)(n0 + row) * DMODEL + k0 + sw * 8,
                  (char*)Bs + (w * 32 + j * 16) * 64);
        }
        __syncthreads();
        bh8 af[4], bg[4];
        #pragma unroll
        for (int mi = 0; mi < 4; ++mi) {
            const int r = wr * 64 + mi * 16 + (l & 15);
            af[mi] = *(const bh8*)((const char*)As + r * 64 +
                                   (((l >> 4) * 16) ^ (((r >> 1) & 3) << 4)));
        }
        #pragma unroll
        for (int ni = 0; ni < 4; ++ni) {
            const int r = wc * 64 + ni * 16 + (l & 15);
            bg[ni] = *(const bh8*)((const char*)Bs + r * 64 +
                                   (((l >> 4) * 16) ^ (((r >> 1) & 3) << 4)));
        }
        #pragma unroll
        for (int mi = 0; mi < 4; ++mi)
            #pragma unroll
            for (int ni = 0; ni < 4; ++ni)
                acc[mi][ni] = MFMA(af[mi], bg[ni], acc[mi][ni]);
    }

    #pragma unroll
    for (int mi = 0; mi < 4; ++mi) {
        #pragma unroll
        for (int rg = 0; rg < 4; ++rg) {
            const int m = m0 + wr * 64 + mi * 16 + (l >> 4) * 4 + rg;
            #pragma unroll
            for (int ni = 0; ni < 4; ++ni) {
                const int n = n0 + wc * 64 + ni * 16 + (l & 15);
                out[(size_t)m * DMODEL + n] = acc[mi][ni][rg];
            }
        }
    }
}

extern "C" void kernel_launch(void* const* d_in, const int* in_sizes, int n_in,
                              void* d_out, int out_size, void* d_ws, size_t ws_size,
                              hipStream_t stream)
{
    const float* x  = (const float*)d_in[0];
    const float* Wq = (const float*)d_in[1];
    const float* Wk = (const float*)d_in[2];
    const float* Wv = (const float*)d_in[3];
    const float* Wo = (const float*)d_in[4];
    float* out = (float*)d_out;

    unsigned short* ws = (unsigned short*)d_ws;
    unsigned short* xb  = ws;                         // 4194304
    unsigned short* Wb  = xb + 4194304;               // 4 x 262144 (q,k,v,o)
    unsigned short* QKV = Wb + 4 * 262144;            // 3 x 4194304 (Q,K,V head-major)
    unsigned short* Vt  = QKV + 3 * 4194304;          // 4194304
    unsigned short* Ow  = Vt + 4194304;               // 4194304
    unsigned short* Qh = QKV;
    unsigned short* Kh = QKV + 4194304;
    unsigned short* Vh = QKV + 2 * 4194304;

    convert_k<<<5120, 256, 0, stream>>>(x, Wq, Wk, Wv, Wo, ws);
    qkv_gemm_mfma<<<dim3(MTOT / 128, DMODEL / 128, 3), 256, 0, stream>>>(xb, Wb, QKV);
    vtrans<<<dim3(SEQ / 64, NBH), 256, 0, stream>>>(Vh, Vt);
    flash_mfma<<<dim3(SEQ / 128, NBH), 256, 0, stream>>>(Qh, Kh, Vt, Ow);
    out_gemm_mfma<<<dim3(MTOT / 128, DMODEL / 128), 256, 0, stream>>>(
        Ow, Wb + 3 * 262144, out);
}

// Round 3
// 145.369 us; speedup vs baseline: 14.4622x; 1.8674x over previous
//
#include <hip/hip_runtime.h>
#include <hip/hip_bf16.h>

#define SEQ 4096
#define DMODEL 512
#define HEADS 8
#define DK 64
#define BATCH 2
#define MTOT (BATCH * SEQ)     // 8192
#define NBH (BATCH * HEADS)    // 16

typedef __attribute__((ext_vector_type(8))) short bh8;    // 8 bf16 (4 VGPR)
typedef __attribute__((ext_vector_type(4))) float f4;
typedef __attribute__((ext_vector_type(16))) float f16x;

#define MFMA(a, b, c)   __builtin_amdgcn_mfma_f32_16x16x32_bf16(a, b, c, 0, 0, 0)
#define MFMA32(a, b, c) __builtin_amdgcn_mfma_f32_32x32x16_bf16(a, b, c, 0, 0, 0)
#define GLL16(g, l) __builtin_amdgcn_global_load_lds( \
    (const __attribute__((address_space(1))) void*)(g), \
    (__attribute__((address_space(3))) void*)(l), 16, 0, 0)

__device__ __forceinline__ unsigned short f2b(float f) {
    union { float f; unsigned u; } v; v.f = f;
    unsigned r = v.u + 0x7fff + ((v.u >> 16) & 1);   // RNE, finite inputs
    return (unsigned short)(r >> 16);
}

__device__ __forceinline__ unsigned cvtpk(float lo, float hi) {
    unsigned r;
    asm("v_cvt_pk_bf16_f32 %0, %1, %2" : "=v"(r) : "v"(lo), "v"(hi));
    return r;
}
// swaps a.hi32lanes <-> b.lo32lanes:  a' = {a.lo, b.lo},  b' = {a.hi, b.hi}
__device__ __forceinline__ void plswap(unsigned& a, unsigned& b) {
    asm("v_permlane32_swap_b32 %0, %1" : "+v"(a), "+v"(b));
}
// every lane gets op(x[l&31], x[l|32])
__device__ __forceinline__ float wave_max_pair(float x) {
    float b = x; asm("" : "+v"(b));      // force distinct register
    float a = x;
    asm("v_permlane32_swap_b32 %0, %1" : "+v"(a), "+v"(b));
    return fmaxf(a, b);
}
__device__ __forceinline__ float wave_sum_pair(float x) {
    float b = x; asm("" : "+v"(b));
    float a = x;
    asm("v_permlane32_swap_b32 %0, %1" : "+v"(a), "+v"(b));
    return a + b;
}

// ---------------------------------------------------------------------------
// fp32 -> bf16 conversion: [x | wq | wk | wv | wo]
// ---------------------------------------------------------------------------
__global__ __launch_bounds__(256) void convert_k(
    const float* __restrict__ x, const float* __restrict__ wq,
    const float* __restrict__ wk, const float* __restrict__ wv,
    const float* __restrict__ wo, unsigned short* __restrict__ dst)
{
    const size_t i = ((size_t)blockIdx.x * 256 + threadIdx.x) * 4;
    const float* s; size_t o;
    if (i < 4194304u)                 { s = x;  o = i; }
    else if (i < 4194304u + 262144u)  { s = wq; o = i - 4194304u; }
    else if (i < 4194304u + 524288u)  { s = wk; o = i - (4194304u + 262144u); }
    else if (i < 4194304u + 786432u)  { s = wv; o = i - (4194304u + 524288u); }
    else                              { s = wo; o = i - (4194304u + 786432u); }
    float4 v = *(const float4*)(s + o);
    ushort4 u; u.x = f2b(v.x); u.y = f2b(v.y); u.z = f2b(v.z); u.w = f2b(v.w);
    *(ushort4*)(dst + i) = u;
}

// ---------------------------------------------------------------------------
// QKV projection (MFMA, 128x128 tile). Q pre-scaled by 0.125*log2(e) so the
// flash kernel can use exp2 directly (softmax is base-invariant).
// ---------------------------------------------------------------------------
__global__ __launch_bounds__(256) void qkv_gemm_mfma(
    const unsigned short* __restrict__ xb,
    const unsigned short* __restrict__ Wb,
    unsigned short* __restrict__ QKV)
{
    const int z = blockIdx.z;
    const unsigned short* A = xb;
    const unsigned short* B = Wb + (size_t)z * (DMODEL * DMODEL);
    const int m0 = blockIdx.x * 128, n0 = blockIdx.y * 128;
    const int tid = threadIdx.x, w = tid >> 6, l = tid & 63;
    const int wr = w >> 1, wc = w & 1;

    __shared__ __align__(16) unsigned short As[128 * 32];
    __shared__ __align__(16) unsigned short Bs[128 * 32];

    f4 acc[4][4] = {};
    const int lrow = l >> 2, lslot = l & 3;

    for (int k0 = 0; k0 < DMODEL; k0 += 32) {
        __syncthreads();
        #pragma unroll
        for (int j = 0; j < 2; ++j) {
            const int row = w * 32 + j * 16 + lrow;
            const int sw = lslot ^ ((row >> 1) & 3);
            GLL16(A + (size_t)(m0 + row) * DMODEL + k0 + sw * 8,
                  (char*)As + (w * 32 + j * 16) * 64);
            GLL16(B + (size_t)(n0 + row) * DMODEL + k0 + sw * 8,
                  (char*)Bs + (w * 32 + j * 16) * 64);
        }
        __syncthreads();
        bh8 af[4], bg[4];
        #pragma unroll
        for (int mi = 0; mi < 4; ++mi) {
            const int r = wr * 64 + mi * 16 + (l & 15);
            af[mi] = *(const bh8*)((const char*)As + r * 64 +
                                   (((l >> 4) * 16) ^ (((r >> 1) & 3) << 4)));
        }
        #pragma unroll
        for (int ni = 0; ni < 4; ++ni) {
            const int r = wc * 64 + ni * 16 + (l & 15);
            bg[ni] = *(const bh8*)((const char*)Bs + r * 64 +
                                   (((l >> 4) * 16) ^ (((r >> 1) & 3) << 4)));
        }
        #pragma unroll
        for (int mi = 0; mi < 4; ++mi)
            #pragma unroll
            for (int ni = 0; ni < 4; ++ni)
                acc[mi][ni] = MFMA(af[mi], bg[ni], acc[mi][ni]);
    }

    unsigned short* Out = QKV + (size_t)z * ((size_t)NBH * SEQ * DK);
    // z==0: fold 1/sqrt(dk) * log2(e) into Q (exp2-domain softmax)
    const float sc = (z == 0) ? 0.18033688011112042f : 1.0f;
    #pragma unroll
    for (int mi = 0; mi < 4; ++mi) {
        #pragma unroll
        for (int rg = 0; rg < 4; ++rg) {
            const int m = m0 + wr * 64 + mi * 16 + (l >> 4) * 4 + rg;
            const int b = m >> 12, t = m & (SEQ - 1);
            #pragma unroll
            for (int ni = 0; ni < 4; ++ni) {
                const int n = n0 + wc * 64 + ni * 16 + (l & 15);
                const int h = n >> 6, d = n & 63;
                Out[(((size_t)(b * HEADS + h)) * SEQ + t) * DK + d] =
                    f2b(acc[mi][ni][rg] * sc);
            }
        }
    }
}

// ---------------------------------------------------------------------------
// V [bh][t][d] -> Vt [bh][d][t]
// ---------------------------------------------------------------------------
__global__ __launch_bounds__(256) void vtrans(
    const unsigned short* __restrict__ Vh, unsigned short* __restrict__ Vt)
{
    const int bh = blockIdx.y, t0 = blockIdx.x * 64;
    __shared__ unsigned short L[64][72];
    const unsigned short* src = Vh + ((size_t)bh * SEQ + t0) * DK;
    const int r = threadIdx.x >> 3, c8 = (threadIdx.x & 7) * 8;
    #pragma unroll
    for (int it = 0; it < 2; ++it) {
        const int row = r + it * 32;
        ushort4 a = *(const ushort4*)(src + (size_t)row * DK + c8);
        ushort4 b = *(const ushort4*)(src + (size_t)row * DK + c8 + 4);
        L[row][c8 + 0] = a.x; L[row][c8 + 1] = a.y; L[row][c8 + 2] = a.z; L[row][c8 + 3] = a.w;
        L[row][c8 + 4] = b.x; L[row][c8 + 5] = b.y; L[row][c8 + 6] = b.z; L[row][c8 + 7] = b.w;
    }
    __syncthreads();
    unsigned short* dst = Vt + (size_t)bh * DK * SEQ + t0;
    #pragma unroll
    for (int it = 0; it < 2; ++it) {
        const int d = r + it * 32;
        ushort4 a, b;
        a.x = L[c8 + 0][d]; a.y = L[c8 + 1][d]; a.z = L[c8 + 2][d]; a.w = L[c8 + 3][d];
        b.x = L[c8 + 4][d]; b.y = L[c8 + 5][d]; b.z = L[c8 + 6][d]; b.w = L[c8 + 7][d];
        *(ushort4*)(dst + (size_t)d * SEQ + c8) = a;
        *(ushort4*)(dst + (size_t)d * SEQ + c8 + 4) = b;
    }
}

// ---------------------------------------------------------------------------
// Flash attention, swapped 32x32x16 MFMA, in-register softmax.
// Block = (bh, 128 q rows) = 4 waves x 32 q. Per lane: q = lane&31;
// lane and lane^32 split the kv range of the same q.
//   S^T = mfma(K, Q)   -> col=q, rows=kv  (scores lane-local)
//   O^T = mfma(V^T, P^T) -> col=q, rows=d (rescale lane-uniform)
// P redistributed in-register via cvt_pk_bf16 + permlane32_swap (T12).
// Defer-max (T13, THR=8 in log2 domain), double-buffered K/V staging.
// ---------------------------------------------------------------------------
__global__ __launch_bounds__(256) void flash_mfma(
    const unsigned short* __restrict__ Qh,   // [NBH][SEQ][DK], pre-scaled
    const unsigned short* __restrict__ Kh,   // [NBH][SEQ][DK]
    const unsigned short* __restrict__ Vtp,  // [NBH][DK][SEQ]
    unsigned short* __restrict__ Ow)         // [MTOT][DMODEL] bf16
{
    const int bid = blockIdx.x;
    const int bh = bid & 15, q0 = (bid >> 4) * 128;  // same-bh blocks -> same XCD
    const int tid = threadIdx.x, w = tid >> 6, l = tid & 63;
    const int lq = l & 31, hi = l >> 5;

    __shared__ __align__(16) unsigned short Ks[2][64 * 64];
    __shared__ __align__(16) unsigned short Vs[2][64 * 64];

    const unsigned short* Qb = Qh + (size_t)bh * SEQ * DK;
    const unsigned short* Kb = Kh + (size_t)bh * SEQ * DK;
    const unsigned short* Vb = Vtp + (size_t)bh * DK * SEQ;

    // Q fragments (B-operand): lane holds Q[q0+w*32+lq][ks*16 + hi*8 .. +7]
    bh8 qf[4];
    #pragma unroll
    for (int ks = 0; ks < 4; ++ks)
        qf[ks] = *(const bh8*)(Qb + (size_t)(q0 + w * 32 + lq) * DK + ks * 16 + hi * 8);

    f16x o0 = {}, o1 = {};           // O^T d-tiles (rows d, col q=lq)
    float m_run = -3.0e38f, l_run = 0.f;

    const int srow = l >> 3, sslot = l & 7;

#define STAGE(buf, kv0_) do {                                                 \
    _Pragma("unroll")                                                         \
    for (int j_ = 0; j_ < 2; ++j_) {                                          \
        const int row_ = w * 16 + j_ * 8 + srow;                              \
        const int sw_ = sslot ^ (row_ & 7);                                   \
        GLL16(Kb + (size_t)((kv0_) + row_) * DK + sw_ * 8,                    \
              (char*)Ks[buf] + (w * 16 + j_ * 8) * 128);                      \
        GLL16(Vb + (size_t)row_ * SEQ + (kv0_) + sw_ * 8,                     \
              (char*)Vs[buf] + (w * 16 + j_ * 8) * 128);                      \
    }                                                                         \
} while (0)

    STAGE(0, 0);
    __syncthreads();
    int cur = 0;

    for (int t = 0; t < SEQ / 64; ++t) {
        if (t < SEQ / 64 - 1) STAGE(cur ^ 1, (t + 1) * 64);

        const char* kb = (const char*)Ks[cur];
        const char* vb = (const char*)Vs[cur];

        // ---- S^T = K x Q : rows kv (2 tiles of 32), col q ----
        f16x sa0 = {}, sa1 = {};
        __builtin_amdgcn_s_setprio(1);
        #pragma unroll
        for (int ks = 0; ks < 4; ++ks) {
            const int boff = ks * 32 + hi * 16;
            const int r0 = lq, r1 = 32 + lq;
            bh8 k0 = *(const bh8*)(kb + r0 * 128 + (boff ^ ((r0 & 7) << 4)));
            bh8 k1 = *(const bh8*)(kb + r1 * 128 + (boff ^ ((r1 & 7) << 4)));
            sa0 = MFMA32(k0, qf[ks], sa0);
            sa1 = MFMA32(k1, qf[ks], sa1);
        }
        __builtin_amdgcn_s_setprio(0);

        // ---- online softmax, lane-local (kv of this q split with lane^32) --
        float t0 = -3.0e38f, t1 = -3.0e38f, t2 = -3.0e38f, t3 = -3.0e38f;
        #pragma unroll
        for (int r = 0; r < 16; r += 4) {
            t0 = fmaxf(t0, fmaxf(sa0[r + 0], sa1[r + 0]));
            t1 = fmaxf(t1, fmaxf(sa0[r + 1], sa1[r + 1]));
            t2 = fmaxf(t2, fmaxf(sa0[r + 2], sa1[r + 2]));
            t3 = fmaxf(t3, fmaxf(sa0[r + 3], sa1[r + 3]));
        }
        const float mx = wave_max_pair(fmaxf(fmaxf(t0, t1), fmaxf(t2, t3)));

        const bool skip = __all(mx <= m_run + 8.0f);   // defer-max (log2 dom.)
        float mnew = m_run, corr = 1.0f;
        if (!skip) {
            mnew = fmaxf(m_run, mx);
            corr = __builtin_amdgcn_exp2f(m_run - mnew);
        }

        float p[32];
        #pragma unroll
        for (int r = 0; r < 16; ++r) {
            p[r]      = __builtin_amdgcn_exp2f(sa0[r] - mnew);
            p[16 + r] = __builtin_amdgcn_exp2f(sa1[r] - mnew);
        }
        float a0 = 0.f, a1 = 0.f, a2 = 0.f, a3 = 0.f;
        #pragma unroll
        for (int r = 0; r < 32; r += 4) {
            a0 += p[r + 0]; a1 += p[r + 1]; a2 += p[r + 2]; a3 += p[r + 3];
        }
        const float psum = wave_sum_pair((a0 + a1) + (a2 + a3));

        if (!skip) {
            m_run = mnew;
            l_run = l_run * corr + psum;
            #pragma unroll
            for (int r = 0; r < 16; ++r) { o0[r] *= corr; o1[r] *= corr; }
        } else {
            l_run += psum;
        }

        // ---- P^T -> B-fragments (cvt_pk + permlane32_swap), per 32-kv cb ---
        bh8 pf[4];
        #pragma unroll
        for (int cb = 0; cb < 2; ++cb) {
            const int b0 = cb * 16;
            unsigned k0 = cvtpk(p[b0 + 0],  p[b0 + 1]);
            unsigned k1 = cvtpk(p[b0 + 2],  p[b0 + 3]);
            unsigned k2 = cvtpk(p[b0 + 4],  p[b0 + 5]);
            unsigned k3 = cvtpk(p[b0 + 6],  p[b0 + 7]);
            unsigned k4 = cvtpk(p[b0 + 8],  p[b0 + 9]);
            unsigned k5 = cvtpk(p[b0 + 10], p[b0 + 11]);
            unsigned k6 = cvtpk(p[b0 + 12], p[b0 + 13]);
            unsigned k7 = cvtpk(p[b0 + 14], p[b0 + 15]);
            plswap(k0, k2);   // k0 -> kb0.reg0, k2 -> kb0.reg2
            plswap(k1, k3);   // k1 -> kb0.reg1, k3 -> kb0.reg3
            plswap(k4, k6);   // kb1
            plswap(k5, k7);
            union { unsigned u[4]; bh8 v; } f0, f1;
            f0.u[0] = k0; f0.u[1] = k1; f0.u[2] = k2; f0.u[3] = k3;
            f1.u[0] = k4; f1.u[1] = k5; f1.u[2] = k6; f1.u[3] = k7;
            pf[cb * 2 + 0] = f0.v;
            pf[cb * 2 + 1] = f1.v;
        }

        // ---- O^T += V^T x P^T : rows d (2 tiles of 32), col q ----
        __builtin_amdgcn_s_setprio(1);
        #pragma unroll
        for (int ks = 0; ks < 4; ++ks) {
            const int boff = ks * 32 + hi * 16;
            const int r0 = lq, r1 = 32 + lq;
            bh8 v0 = *(const bh8*)(vb + r0 * 128 + (boff ^ ((r0 & 7) << 4)));
            bh8 v1 = *(const bh8*)(vb + r1 * 128 + (boff ^ ((r1 & 7) << 4)));
            o0 = MFMA32(v0, pf[ks], o0);
            o1 = MFMA32(v1, pf[ks], o1);
        }
        __builtin_amdgcn_s_setprio(0);

        __syncthreads();
        cur ^= 1;
    }
#undef STAGE

    // ---- epilogue: O^T -> row-major via swizzled LDS, coalesced store ----
    const float inv = 1.0f / l_run;
    char* Tb = (char*)Ks + w * 4096;     // per-wave 32 q-rows x 128 B
    #pragma unroll
    for (int db = 0; db < 2; ++db) {
        f16x ov = db ? o1 : o0;
        #pragma unroll
        for (int j = 0; j < 8; ++j) {
            const int r = 2 * j;
            const int d = db * 32 + (r & 3) + 8 * (r >> 2) + 4 * hi;
            unsigned pk = cvtpk(ov[r] * inv, ov[r + 1] * inv);
            *(unsigned*)(Tb + lq * 128 + ((d * 2) ^ ((lq & 7) << 4))) = pk;
        }
    }
    __syncthreads();
    const int b = bh >> 3, h = bh & 7;
    const int row = l >> 1, half = l & 1;
    const int q = q0 + w * 32 + row;
    unsigned short* dst = Ow + ((size_t)b * SEQ + q) * DMODEL + h * DK + half * 32;
    #pragma unroll
    for (int i = 0; i < 4; ++i) {
        const int byte = (half * 64 + i * 16) ^ ((row & 7) << 4);
        uint4 vv = *(const uint4*)(Tb + row * 128 + byte);
        *(uint4*)(dst + i * 8) = vv;
    }
}

// ---------------------------------------------------------------------------
// out = Ow(bf16) @ Wo^T(bf16) -> fp32
// ---------------------------------------------------------------------------
__global__ __launch_bounds__(256) void out_gemm_mfma(
    const unsigned short* __restrict__ Ob,
    const unsigned short* __restrict__ Wob,
    float* __restrict__ out)
{
    const int m0 = blockIdx.x * 128, n0 = blockIdx.y * 128;
    const int tid = threadIdx.x, w = tid >> 6, l = tid & 63;
    const int wr = w >> 1, wc = w & 1;

    __shared__ __align__(16) unsigned short As[128 * 32];
    __shared__ __align__(16) unsigned short Bs[128 * 32];

    f4 acc[4][4] = {};
    const int lrow = l >> 2, lslot = l & 3;

    for (int k0 = 0; k0 < DMODEL; k0 += 32) {
        __syncthreads();
        #pragma unroll
        for (int j = 0; j < 2; ++j) {
            const int row = w * 32 + j * 16 + lrow;
            const int sw = lslot ^ ((row >> 1) & 3);
            GLL16(Ob + (size_t)(m0 + row) * DMODEL + k0 + sw * 8,
                  (char*)As + (w * 32 + j * 16) * 64);
            GLL16(Wob + (size_t)(n0 + row) * DMODEL + k0 + sw * 8,
                  (char*)Bs + (w * 32 + j * 16) * 64);
        }
        __syncthreads();
        bh8 af[4], bg[4];
        #pragma unroll
        for (int mi = 0; mi < 4; ++mi) {
            const int r = wr * 64 + mi * 16 + (l & 15);
            af[mi] = *(const bh8*)((const char*)As + r * 64 +
                                   (((l >> 4) * 16) ^ (((r >> 1) & 3) << 4)));
        }
        #pragma unroll
        for (int ni = 0; ni < 4; ++ni) {
            const int r = wc * 64 + ni * 16 + (l & 15);
            bg[ni] = *(const bh8*)((const char*)Bs + r * 64 +
                                   (((l >> 4) * 16) ^ (((r >> 1) & 3) << 4)));
        }
        #pragma unroll
        for (int mi = 0; mi < 4; ++mi)
            #pragma unroll
            for (int ni = 0; ni < 4; ++ni)
                acc[mi][ni] = MFMA(af[mi], bg[ni], acc[mi][ni]);
    }

    #pragma unroll
    for (int mi = 0; mi < 4; ++mi) {
        #pragma unroll
        for (int rg = 0; rg < 4; ++rg) {
            const int m = m0 + wr * 64 + mi * 16 + (l >> 4) * 4 + rg;
            #pragma unroll
            for (int ni = 0; ni < 4; ++ni) {
                const int n = n0 + wc * 64 + ni * 16 + (l & 15);
                out[(size_t)m * DMODEL + n] = acc[mi][ni][rg];
            }
        }
    }
}

extern "C" void kernel_launch(void* const* d_in, const int* in_sizes, int n_in,
                              void* d_out, int out_size, void* d_ws, size_t ws_size,
                              hipStream_t stream)
{
    const float* x  = (const float*)d_in[0];
    const float* Wq = (const float*)d_in[1];
    const float* Wk = (const float*)d_in[2];
    const float* Wv = (const float*)d_in[3];
    const float* Wo = (const float*)d_in[4];
    float* out = (float*)d_out;

    unsigned short* ws = (unsigned short*)d_ws;
    unsigned short* xb  = ws;                         // 4194304
    unsigned short* Wb  = xb + 4194304;               // 4 x 262144 (q,k,v,o)
    unsigned short* QKV = Wb + 4 * 262144;            // 3 x 4194304
    unsigned short* Vt  = QKV + 3 * 4194304;          // 4194304
    unsigned short* Ow  = Vt + 4194304;               // 4194304
    unsigned short* Qh = QKV;
    unsigned short* Kh = QKV + 4194304;
    unsigned short* Vh = QKV + 2 * 4194304;

    convert_k<<<5120, 256, 0, stream>>>(x, Wq, Wk, Wv, Wo, ws);
    qkv_gemm_mfma<<<dim3(MTOT / 128, DMODEL / 128, 3), 256, 0, stream>>>(xb, Wb, QKV);
    vtrans<<<dim3(SEQ / 64, NBH), 256, 0, stream>>>(Vh, Vt);
    flash_mfma<<<512, 256, 0, stream>>>(Qh, Kh, Vt, Ow);
    out_gemm_mfma<<<dim3(MTOT / 128, DMODEL / 128), 256, 0, stream>>>(
        Ow, Wb + 3 * 262144, out);
}